// Round 1
// baseline (425.617 us; speedup 1.0000x reference)
//
#include <hip/hip_runtime.h>

// ChessboardLayer: space-to-depth into 8x8 cell grid.
// Input  (B=32, H=256, W=256, C=32) fp32, NHWC contiguous.
// Output (B, 8, 8, 32768) fp32.
//
// Key fact: for fixed (b, i, j, r) the inner (w2, c) span of ww*C = 1024
// floats is contiguous in BOTH input and output. So the whole op is a
// permutation of 65536 contiguous 4 KiB blocks.
//
// out 4KiB-block index: blk = ((b*8 + i)*8 + j)*32 + r
// in  4KiB-block index: ((b*256 + i*32 + r)*8 + j)
//
// One 256-thread workgroup copies exactly one 4 KiB block
// (256 lanes x float4 = 4096 B), fully coalesced on both sides.

__global__ __launch_bounds__(256) void chessboard_kernel(
    const float4* __restrict__ in, float4* __restrict__ out) {
    unsigned g      = blockIdx.x * 256u + threadIdx.x;   // global float4 index
    unsigned within = g & 255u;                          // float4 within 4KiB block
    unsigned blk    = g >> 8;                            // output block index

    unsigned r = blk & 31u;
    unsigned j = (blk >> 5) & 7u;
    unsigned i = (blk >> 8) & 7u;
    unsigned b = blk >> 11;

    unsigned in_blk = (b * 256u + i * 32u + r) * 8u + j;
    out[g] = in[in_blk * 256u + within];
}

extern "C" void kernel_launch(void* const* d_in, const int* in_sizes, int n_in,
                              void* d_out, int out_size, void* d_ws, size_t ws_size,
                              hipStream_t stream) {
    const float4* in  = (const float4*)d_in[0];
    float4*       out = (float4*)d_out;
    // 32*256*256*32 floats = 16,777,216 float4 = 65,536 blocks of 256 threads
    chessboard_kernel<<<65536, 256, 0, stream>>>(in, out);
}